// Round 1
// baseline (230.028 us; speedup 1.0000x reference)
//
#include <hip/hip_runtime.h>

// WeightedTensorProduct: N=16384 nodes, F=128 features, ranks 0..3 (sizes 1,3,9,27).
// x,y: [N, F*40] f32 (per-row layout: [F] | [F][3] | [F][9] | [F][27]).
// weights: [23][F] f32. out: [N, F*40] f32, same layout as inputs.

#define FF 128
#define ROW 5120   // F * 40

// Path norms, order p = (l3 outer, l1, l2 inner), 23 even-parity paths.
__device__ __constant__ float NORMS[23] = {
    1.0f, 1.0f, 2.0f/3.0f, 0.4f,                    // (0,0,0)(1,1,0)(2,2,0)(3,3,0)
    1.0f, 1.0f, 1.0f, 1.0f, 2.0f/3.0f, 2.0f/3.0f,   // (0,1,1)(1,0,1)(1,2,1)(2,1,1)(2,3,1)(3,2,1)
    1.0f, 0.75f, 1.0f, 1.0f, 1.0f, 1.0f, 0.75f,     // (0,2,2)(1,1,2)(1,3,2)(2,0,2)(2,2,2)(3,1,2)(3,3,2)
    1.0f, 5.0f/9.0f, 5.0f/9.0f, 5.0f/6.0f, 1.0f, 5.0f/6.0f // (0,3,3)(1,2,3)(2,1,3)(2,3,3)(3,0,3)(3,2,3)
};

__global__ __launch_bounds__(256) void wtp_kernel(
    const float* __restrict__ x, const float* __restrict__ y,
    const float* __restrict__ w, float* __restrict__ out)
{
    __shared__ float cs[23][FF];   // norm * weight, staged once per block
    const int tid = threadIdx.x;
    for (int i = tid; i < 23 * FF; i += 256) {
        cs[i >> 7][i & 127] = NORMS[i >> 7] * w[i];
    }
    __syncthreads();

    const int n = blockIdx.x * 2 + (tid >> 7);   // 2 nodes per 256-thread block
    const int f = tid & 127;

    const float* xr = x + (size_t)n * ROW;
    const float* yr = y + (size_t)n * ROW;

    // ---- load x,y blocks for this (n,f) ----
    const float x0 = xr[f];
    const float y0 = yr[f];
    float x1[3], y1[3], x2[9], y2[9], x3[27], y3[27];
    #pragma unroll
    for (int j = 0; j < 3; ++j)  x1[j] = xr[128  + f*3  + j];
    #pragma unroll
    for (int j = 0; j < 3; ++j)  y1[j] = yr[128  + f*3  + j];
    #pragma unroll
    for (int j = 0; j < 9; ++j)  x2[j] = xr[512  + f*9  + j];
    #pragma unroll
    for (int j = 0; j < 9; ++j)  y2[j] = yr[512  + f*9  + j];
    #pragma unroll
    for (int j = 0; j < 27; ++j) x3[j] = xr[1664 + f*27 + j];
    #pragma unroll
    for (int j = 0; j < 27; ++j) y3[j] = yr[1664 + f*27 + j];

    const float c0  = cs[0][f],  c1  = cs[1][f],  c2  = cs[2][f],  c3  = cs[3][f];
    const float c4  = cs[4][f],  c5  = cs[5][f],  c6  = cs[6][f],  c7  = cs[7][f];
    const float c8  = cs[8][f],  c9  = cs[9][f],  c10 = cs[10][f], c11 = cs[11][f];
    const float c12 = cs[12][f], c13 = cs[13][f], c14 = cs[14][f], c15 = cs[15][f];
    const float c16 = cs[16][f], c17 = cs[17][f], c18 = cs[18][f], c19 = cs[19][f];
    const float c20 = cs[20][f], c21 = cs[21][f], c22 = cs[22][f];

    float* orow = out + (size_t)n * ROW;

    // ---- l3 = 0 ----
    {
        float acc = c0 * (x0 * y0);
        float d3 = 0.f;
        #pragma unroll
        for (int u = 0; u < 3; ++u) d3 += x1[u] * y1[u];
        acc += c1 * d3;
        float d9 = 0.f;
        #pragma unroll
        for (int t = 0; t < 9; ++t) d9 += x2[t] * y2[t];
        acc += c2 * d9;
        float d27 = 0.f;
        #pragma unroll
        for (int t = 0; t < 27; ++t) d27 += x3[t] * y3[t];
        acc += c3 * d27;
        orow[f] = acc;
    }

    // ---- l3 = 1 ----
    #pragma unroll
    for (int d = 0; d < 3; ++d) {
        float acc = c4 * (x0 * y1[d]) + c5 * (x1[d] * y0);
        float s6 = 0.f, s7 = 0.f, s8 = 0.f, s9 = 0.f;
        #pragma unroll
        for (int u = 0; u < 3; ++u) s6 += x1[u] * y2[u*3 + d];     // (1,2,1)
        #pragma unroll
        for (int u = 0; u < 3; ++u) s7 += x2[d*3 + u] * y1[u];     // (2,1,1)
        #pragma unroll
        for (int t = 0; t < 9; ++t) s8 += x2[t] * y3[t*3 + d];     // (2,3,1)
        #pragma unroll
        for (int t = 0; t < 9; ++t) s9 += x3[d*9 + t] * y2[t];     // (3,2,1)
        acc += c6 * s6 + c7 * s7 + c8 * s8 + c9 * s9;
        orow[128 + f*3 + d] = acc;
    }

    // ---- l3 = 2 ----  (t = a*3 + d)
    #pragma unroll
    for (int t = 0; t < 9; ++t) {
        const int a = t / 3, d = t % 3;
        float acc = c10 * (x0 * y2[t]) + c11 * (x1[a] * y1[d]) + c13 * (x2[t] * y0);
        float s12 = 0.f, s14 = 0.f, s15 = 0.f, s16 = 0.f;
        #pragma unroll
        for (int u = 0; u < 3; ++u) s12 += x1[u] * y3[u*9 + t];         // (1,3,2)
        #pragma unroll
        for (int u = 0; u < 3; ++u) s14 += x2[a*3 + u] * y2[u*3 + d];   // (2,2,2)
        #pragma unroll
        for (int u = 0; u < 3; ++u) s15 += x3[t*3 + u] * y1[u];         // (3,1,2)
        #pragma unroll
        for (int s = 0; s < 9; ++s) s16 += x3[a*9 + s] * y3[s*3 + d];   // (3,3,2)
        acc += c12 * s12 + c14 * s14 + c15 * s15 + c16 * s16;
        orow[512 + f*9 + t] = acc;
    }

    // ---- l3 = 3 ----  (q = a*9 + t9, also q = r*3 + e)
    #pragma unroll
    for (int q = 0; q < 27; ++q) {
        const int a = q / 9, t9 = q % 9, r = q / 3, e = q % 3;
        float acc = c17 * (x0 * y3[q]) + c18 * (x1[a] * y2[t9])
                  + c19 * (x2[r] * y1[e]) + c21 * (x3[q] * y0);
        float s20 = 0.f, s22 = 0.f;
        #pragma unroll
        for (int u = 0; u < 3; ++u) s20 += x2[a*3 + u] * y3[u*9 + t9];  // (2,3,3)
        #pragma unroll
        for (int u = 0; u < 3; ++u) s22 += x3[r*3 + u] * y2[u*3 + e];   // (3,2,3)
        acc += c20 * s20 + c22 * s22;
        orow[1664 + f*27 + q] = acc;
    }
}

extern "C" void kernel_launch(void* const* d_in, const int* in_sizes, int n_in,
                              void* d_out, int out_size, void* d_ws, size_t ws_size,
                              hipStream_t stream) {
    const float* x = (const float*)d_in[0];
    const float* y = (const float*)d_in[1];
    const float* w = (const float*)d_in[2];
    float* out = (float*)d_out;

    const int n_nodes = in_sizes[0] / ROW;        // 16384
    dim3 grid(n_nodes / 2), block(256);           // 2 nodes per block
    hipLaunchKernelGGL(wtp_kernel, grid, block, 0, stream, x, y, w, out);
}